// Round 24
// baseline (86.336 us; speedup 1.0000x reference)
//
#include <hip/hip_runtime.h>
#include <cstdint>

#define BB 256
#define NN 128
#define DD 512
#define HH 512

typedef __attribute__((ext_vector_type(8))) short bf16x8;
typedef __attribute__((ext_vector_type(16))) float f32x16;
typedef unsigned short u16;

static __device__ __forceinline__ u16 f2bf(float f) {
    union { float f; uint32_t u; } v; v.f = f;
    uint32_t u = v.u;
    return (u16)((u + 0x7FFFu + ((u >> 16) & 1u)) >> 16);
}

static __device__ __forceinline__ void gload16(const u16* g, u16* l) {
    __builtin_amdgcn_global_load_lds((const __attribute__((address_space(1))) void*)g,
                                     (__attribute__((address_space(3))) void*)l, 16, 0, 0);
}

// ---------------- W fp32 -> bf16 TRANSPOSED chunk-major: Wt[kc][h][8]  (R17-verified) ----------------
__global__ __launch_bounds__(256) void wconv_kernel(const float* __restrict__ W, u16* __restrict__ Wt) {
    int idx = (blockIdx.x * 256 + threadIdx.x) * 4;
    int h = idx >> 9, d = idx & 511;
    float4 v = *(const float4*)(W + idx);
    ushort4 o;
    o.x = f2bf(v.x); o.y = f2bf(v.y); o.z = f2bf(v.z); o.w = f2bf(v.w);
    *(ushort4*)(Wt + ((size_t)(d >> 3) * HH + h) * 8 + (d & 7)) = o;
}

// ---------------- Xagg = (I + A_norm) @ X -> HBM bf16  (R12/R17-verified) ----------------
__global__ __launch_bounds__(512) void agg_kernel(const float* __restrict__ X, const float* __restrict__ A,
                                                  u16* __restrict__ Xagg) {
    __shared__ __align__(16) char smem[163840];
    u16* Ms = (u16*)smem;                 // [128 i][128 m], chunk c' = c ^ (i&15)
    u16* Xt = (u16*)(smem + 32768);       // [512 d][128 m], chunk c' = c ^ ((d>>2)&7)

    const int t = threadIdx.x;
    const int lane = t & 63, w = t >> 6, l31 = lane & 31, lh = lane >> 5;
    const int batch = blockIdx.x;
    const int wm = w >> 2, wn = w & 3;

    {
        const int row = t >> 2, seg = t & 3;
        const float* Ag = A + (size_t)batch * NN * NN + row * NN + seg * 32;
        float4 a[8];
        #pragma unroll
        for (int j = 0; j < 8; ++j) a[j] = *(const float4*)(Ag + j * 4);
        float s = 0.f;
        #pragma unroll
        for (int j = 0; j < 8; ++j) s += a[j].x + a[j].y + a[j].z + a[j].w;
        s += __shfl_xor(s, 1);
        s += __shfl_xor(s, 2);
        const float inv = 1.0f / (s + 1e-6f);
        #pragma unroll
        for (int c2 = 0; c2 < 4; ++c2) {
            u16 tmp[8];
            const float* pe = (const float*)&a[c2 * 2];
            #pragma unroll
            for (int e = 0; e < 8; ++e) {
                int m = seg * 32 + c2 * 8 + e;
                tmp[e] = f2bf(pe[e] * inv + (m == row ? 1.0f : 0.0f));
            }
            int c = seg * 4 + c2;
            *(uint4*)(Ms + row * 128 + ((c ^ (row & 15)) << 3)) = *(const uint4*)tmp;
        }
    }

    {
        const float* Xg = X + (size_t)batch * NN * DD;
        #pragma unroll
        for (int it = 0; it < 32; ++it) {
            int q = it * 512 + t;
            int m = q >> 7, c4 = q & 127;
            float4 v = *(const float4*)(Xg + (size_t)m * DD + c4 * 4);
            float fv[4] = {v.x, v.y, v.z, v.w};
            #pragma unroll
            for (int j = 0; j < 4; ++j) {
                int d = c4 * 4 + j;
                Xt[d * 128 + (((m >> 3) ^ ((d >> 2) & 7)) << 3) + (m & 7)] = f2bf(fv[j]);
            }
        }
    }
    __syncthreads();

    u16* Og = Xagg + (size_t)batch * NN * DD;
    #pragma unroll
    for (int dh = 0; dh < 2; ++dh) {
        f32x16 acc1[2][2];
        #pragma unroll
        for (int fi = 0; fi < 2; ++fi)
            #pragma unroll
            for (int fd = 0; fd < 2; ++fd)
                #pragma unroll
                for (int r = 0; r < 16; ++r)
                    acc1[fi][fd][r] = 0.f;

        #pragma unroll
        for (int ksl = 0; ksl < 8; ++ksl) {
            const int kc = ksl * 2 + lh;
            bf16x8 af[2], bx[2];
            #pragma unroll
            for (int fi = 0; fi < 2; ++fi) {
                int i = wm * 64 + fi * 32 + l31;
                af[fi] = *(const bf16x8*)(Ms + i * 128 + ((kc ^ (i & 15)) << 3));
            }
            #pragma unroll
            for (int fd = 0; fd < 2; ++fd) {
                int d = dh * 256 + wn * 64 + fd * 32 + l31;
                bx[fd] = *(const bf16x8*)(Xt + d * 128 + ((kc ^ ((d >> 2) & 7)) << 3));
            }
            #pragma unroll
            for (int fi = 0; fi < 2; ++fi)
                #pragma unroll
                for (int fd = 0; fd < 2; ++fd)
                    acc1[fi][fd] = __builtin_amdgcn_mfma_f32_32x32x16_bf16(af[fi], bx[fd], acc1[fi][fd], 0, 0, 0);
        }

        #pragma unroll
        for (int fi = 0; fi < 2; ++fi)
            #pragma unroll
            for (int r = 0; r < 16; ++r) {
                int i = wm * 64 + fi * 32 + (r & 3) + 8 * (r >> 2) + 4 * lh;
                #pragma unroll
                for (int fd = 0; fd < 2; ++fd) {
                    int d = dh * 256 + wn * 64 + fd * 32 + l31;
                    Og[(size_t)i * DD + d] = f2bf(acc1[fi][fd][r]);
                }
            }
    }
}

// ---------------- out = sigmoid(LN( Xagg @ W^T + bias )) ----------------
// grid 512 (M-tile 64), 512 thr = 8 waves; wave w -> h strip [64w, 64w+64).
// LDS = 32 KB (X K-half [64 m][256 k]), K in 2 halves with restage (R18 structure).
// W direct from transposed Wt (coalesced 512B frags, L2; 0 conflicts).
// __launch_bounds__(512, 2): 128-VGPR tier — acc[2][2]=64 + frags ~100 live fits
// CLEAN (R18's (512,3) put this exact kernel on the 84-reg tier and spilled:
// steady WRITE 183 MB -> 92 us). 2 blocks x 8 waves = 16 waves/CU; Wt traffic
// halved vs M-tile-32 (256 MB total L2).
__global__ __launch_bounds__(512, 2) void gemm_ln_kernel(const u16* __restrict__ Xagg, const u16* __restrict__ Wt,
                                                         const float* __restrict__ bias, const float* __restrict__ lnw,
                                                         const float* __restrict__ lnb, float* __restrict__ out) {
    __shared__ __align__(16) char smem[32768];   // X half-tile; stats overlay after K-loop
    float* Pss = (float*)smem;                   // [8 w][64 row][2]
    float* musig = (float*)(smem + 4096);        // [64 row][2]

    const int t = threadIdx.x;
    const int lane = t & 63, w = t >> 6, l31 = lane & 31, lh = lane >> 5;
    const size_t rb = (size_t)blockIdx.x * 64;
    const u16* Xab = Xagg + rb * DD;

    float bias_v[2], lnw_v[2], lnb_v[2];
    #pragma unroll
    for (int fh = 0; fh < 2; ++fh) {
        int h = w * 64 + fh * 32 + l31;
        bias_v[fh] = bias[h];
        lnw_v[fh] = lnw[h];
        lnb_v[fh] = lnb[h];
    }

    f32x16 acc[2][2];   // [mi][fh]
    #pragma unroll
    for (int mi = 0; mi < 2; ++mi)
        #pragma unroll
        for (int fh = 0; fh < 2; ++fh)
            #pragma unroll
            for (int r = 0; r < 16; ++r)
                acc[mi][fh][r] = 0.f;

    const u16* al = (const u16*)smem;
    #pragma unroll
    for (int kh = 0; kh < 2; ++kh) {
        // stage X K-half: linear LDS dest, inverse-swizzled source (c' = c ^ (m&15), c in [0,32))
        #pragma unroll
        for (int it = 0; it < 4; ++it) {
            int q = it * 512 + t;
            int m = q >> 5, cp = q & 31;
            gload16(Xab + (size_t)m * DD + kh * 256 + ((cp ^ (m & 15)) * 8), (u16*)smem + q * 8);
        }
        __syncthreads();   // drain gloads; half ready

        #pragma unroll
        for (int st = 0; st < 16; ++st) {
            const int c16 = st * 2 + lh;          // within-half 16B chunk [0,32)
            const int gc = kh * 32 + c16;         // global chunk for Wt
            bf16x8 af[2], bw[2];
            #pragma unroll
            for (int mi = 0; mi < 2; ++mi) {
                int m = mi * 32 + l31;
                af[mi] = *(const bf16x8*)(al + (m * 32 + (c16 ^ (m & 15))) * 8);
            }
            #pragma unroll
            for (int fh = 0; fh < 2; ++fh) {
                int h = w * 64 + fh * 32 + l31;
                bw[fh] = *(const bf16x8*)(Wt + ((size_t)gc * HH + h) * 8);
            }
            #pragma unroll
            for (int mi = 0; mi < 2; ++mi)
                #pragma unroll
                for (int fh = 0; fh < 2; ++fh)
                    acc[mi][fh] = __builtin_amdgcn_mfma_f32_32x32x16_bf16(af[mi], bw[fh], acc[mi][fh], 0, 0, 0);
        }
        __syncthreads();   // all reads done before restage / stats overlay
    }

    // bias + per-row partial stats over this wave's 64 h  (R17/R18-verified epilogue)
    float rs[2][16], rss[2][16];
    #pragma unroll
    for (int mi = 0; mi < 2; ++mi)
        #pragma unroll
        for (int r = 0; r < 16; ++r) {
            float a0 = acc[mi][0][r] + bias_v[0];
            float a1 = acc[mi][1][r] + bias_v[1];
            acc[mi][0][r] = a0; acc[mi][1][r] = a1;
            rs[mi][r] = a0 + a1;
            rss[mi][r] = a0 * a0 + a1 * a1;
        }
    #pragma unroll
    for (int msk = 1; msk <= 16; msk <<= 1)
        #pragma unroll
        for (int mi = 0; mi < 2; ++mi)
            #pragma unroll
            for (int r = 0; r < 16; ++r) {
                rs[mi][r] += __shfl_xor(rs[mi][r], msk);
                rss[mi][r] += __shfl_xor(rss[mi][r], msk);
            }
    if (l31 == 0) {
        #pragma unroll
        for (int mi = 0; mi < 2; ++mi)
            #pragma unroll
            for (int r = 0; r < 16; ++r) {
                int rl = mi * 32 + (r & 3) + 8 * (r >> 2) + 4 * lh;
                float2 v; v.x = rs[mi][r]; v.y = rss[mi][r];
                *(float2*)(Pss + (w * 64 + rl) * 2) = v;
            }
    }
    __syncthreads();
    if (t < 64) {
        float s = 0.f, ss = 0.f;
        #pragma unroll
        for (int q = 0; q < 8; ++q) {
            float2 v = *(const float2*)(Pss + (q * 64 + t) * 2);
            s += v.x; ss += v.y;
        }
        float mean = s * (1.0f / 512.0f);
        float var = ss * (1.0f / 512.0f) - mean * mean;
        float2 mz; mz.x = mean; mz.y = rsqrtf(var + 1e-5f);
        *(float2*)(musig + t * 2) = mz;
    }
    __syncthreads();

    #pragma unroll
    for (int mi = 0; mi < 2; ++mi)
        #pragma unroll
        for (int r = 0; r < 16; ++r) {
            int rl = mi * 32 + (r & 3) + 8 * (r >> 2) + 4 * lh;
            float2 mz = *(const float2*)(musig + rl * 2);
            #pragma unroll
            for (int fh = 0; fh < 2; ++fh) {
                float xn = (acc[mi][fh][r] - mz.x) * mz.y * lnw_v[fh] + lnb_v[fh];
                out[(rb + rl) * HH + w * 64 + fh * 32 + l31] = 1.0f / (1.0f + __expf(-xn));
            }
        }
}

extern "C" void kernel_launch(void* const* d_in, const int* in_sizes, int n_in,
                              void* d_out, int out_size, void* d_ws, size_t ws_size,
                              hipStream_t stream) {
    const float* X = (const float*)d_in[0];
    const float* A = (const float*)d_in[1];
    const float* W = (const float*)d_in[2];
    const float* bias = (const float*)d_in[3];
    const float* lnw = (const float*)d_in[4];
    const float* lnb = (const float*)d_in[5];
    float* out = (float*)d_out;

    u16* Xagg = (u16*)d_ws;                                  // B*N*D bf16 = 32 MB
    u16* Wt = (u16*)d_ws + (size_t)BB * NN * DD;             // transposed W bf16 = 512 KB

    hipLaunchKernelGGL(wconv_kernel, dim3(256), dim3(256), 0, stream, W, Wt);
    hipLaunchKernelGGL(agg_kernel, dim3(256), dim3(512), 0, stream, X, A, Xagg);
    hipLaunchKernelGGL(gemm_ln_kernel, dim3(512), dim3(512), 0, stream, Xagg, Wt, bias, lnw, lnb, out);
}

// Round 25
// 71.424 us; speedup vs baseline: 1.2088x; 1.2088x over previous
//
#include <hip/hip_runtime.h>
#include <cstdint>

#define BB 256
#define NN 128
#define DD 512
#define HH 512

typedef __attribute__((ext_vector_type(8))) short bf16x8;
typedef __attribute__((ext_vector_type(16))) float f32x16;
typedef unsigned short u16;

static __device__ __forceinline__ u16 f2bf(float f) {
    union { float f; uint32_t u; } v; v.f = f;
    uint32_t u = v.u;
    return (u16)((u + 0x7FFFu + ((u >> 16) & 1u)) >> 16);
}

static __device__ __forceinline__ void gload16(const u16* g, u16* l) {
    __builtin_amdgcn_global_load_lds((const __attribute__((address_space(1))) void*)g,
                                     (__attribute__((address_space(3))) void*)l, 16, 0, 0);
}

// ---------------- W fp32 -> bf16 TRANSPOSED chunk-major: Wt[kc][h][8]  (R17-verified) ----------------
__global__ __launch_bounds__(256) void wconv_kernel(const float* __restrict__ W, u16* __restrict__ Wt) {
    int idx = (blockIdx.x * 256 + threadIdx.x) * 4;
    int h = idx >> 9, d = idx & 511;
    float4 v = *(const float4*)(W + idx);
    ushort4 o;
    o.x = f2bf(v.x); o.y = f2bf(v.y); o.z = f2bf(v.z); o.w = f2bf(v.w);
    *(ushort4*)(Wt + ((size_t)(d >> 3) * HH + h) * 8 + (d & 7)) = o;
}

// ---------------- Xagg = (I + A_norm) @ X -> HBM bf16  (R12/R17-verified) ----------------
__global__ __launch_bounds__(512) void agg_kernel(const float* __restrict__ X, const float* __restrict__ A,
                                                  u16* __restrict__ Xagg) {
    __shared__ __align__(16) char smem[163840];
    u16* Ms = (u16*)smem;                 // [128 i][128 m], chunk c' = c ^ (i&15)
    u16* Xt = (u16*)(smem + 32768);       // [512 d][128 m], chunk c' = c ^ ((d>>2)&7)

    const int t = threadIdx.x;
    const int lane = t & 63, w = t >> 6, l31 = lane & 31, lh = lane >> 5;
    const int batch = blockIdx.x;
    const int wm = w >> 2, wn = w & 3;

    {
        const int row = t >> 2, seg = t & 3;
        const float* Ag = A + (size_t)batch * NN * NN + row * NN + seg * 32;
        float4 a[8];
        #pragma unroll
        for (int j = 0; j < 8; ++j) a[j] = *(const float4*)(Ag + j * 4);
        float s = 0.f;
        #pragma unroll
        for (int j = 0; j < 8; ++j) s += a[j].x + a[j].y + a[j].z + a[j].w;
        s += __shfl_xor(s, 1);
        s += __shfl_xor(s, 2);
        const float inv = 1.0f / (s + 1e-6f);
        #pragma unroll
        for (int c2 = 0; c2 < 4; ++c2) {
            u16 tmp[8];
            const float* pe = (const float*)&a[c2 * 2];
            #pragma unroll
            for (int e = 0; e < 8; ++e) {
                int m = seg * 32 + c2 * 8 + e;
                tmp[e] = f2bf(pe[e] * inv + (m == row ? 1.0f : 0.0f));
            }
            int c = seg * 4 + c2;
            *(uint4*)(Ms + row * 128 + ((c ^ (row & 15)) << 3)) = *(const uint4*)tmp;
        }
    }

    {
        const float* Xg = X + (size_t)batch * NN * DD;
        #pragma unroll
        for (int it = 0; it < 32; ++it) {
            int q = it * 512 + t;
            int m = q >> 7, c4 = q & 127;
            float4 v = *(const float4*)(Xg + (size_t)m * DD + c4 * 4);
            float fv[4] = {v.x, v.y, v.z, v.w};
            #pragma unroll
            for (int j = 0; j < 4; ++j) {
                int d = c4 * 4 + j;
                Xt[d * 128 + (((m >> 3) ^ ((d >> 2) & 7)) << 3) + (m & 7)] = f2bf(fv[j]);
            }
        }
    }
    __syncthreads();

    u16* Og = Xagg + (size_t)batch * NN * DD;
    #pragma unroll
    for (int dh = 0; dh < 2; ++dh) {
        f32x16 acc1[2][2];
        #pragma unroll
        for (int fi = 0; fi < 2; ++fi)
            #pragma unroll
            for (int fd = 0; fd < 2; ++fd)
                #pragma unroll
                for (int r = 0; r < 16; ++r)
                    acc1[fi][fd][r] = 0.f;

        #pragma unroll
        for (int ksl = 0; ksl < 8; ++ksl) {
            const int kc = ksl * 2 + lh;
            bf16x8 af[2], bx[2];
            #pragma unroll
            for (int fi = 0; fi < 2; ++fi) {
                int i = wm * 64 + fi * 32 + l31;
                af[fi] = *(const bf16x8*)(Ms + i * 128 + ((kc ^ (i & 15)) << 3));
            }
            #pragma unroll
            for (int fd = 0; fd < 2; ++fd) {
                int d = dh * 256 + wn * 64 + fd * 32 + l31;
                bx[fd] = *(const bf16x8*)(Xt + d * 128 + ((kc ^ ((d >> 2) & 7)) << 3));
            }
            #pragma unroll
            for (int fi = 0; fi < 2; ++fi)
                #pragma unroll
                for (int fd = 0; fd < 2; ++fd)
                    acc1[fi][fd] = __builtin_amdgcn_mfma_f32_32x32x16_bf16(af[fi], bx[fd], acc1[fi][fd], 0, 0, 0);
        }

        #pragma unroll
        for (int fi = 0; fi < 2; ++fi)
            #pragma unroll
            for (int r = 0; r < 16; ++r) {
                int i = wm * 64 + fi * 32 + (r & 3) + 8 * (r >> 2) + 4 * lh;
                #pragma unroll
                for (int fd = 0; fd < 2; ++fd) {
                    int d = dh * 256 + wn * 64 + fd * 32 + l31;
                    Og[(size_t)i * DD + d] = f2bf(acc1[fi][fd][r]);
                }
            }
    }
}

// ---------------- out = sigmoid(LN( Xagg @ W^T + bias )) ----------------
// grid 1024 (M-tile 32), 256 thr = 4 waves; wave w -> h strip [128w, 128w+128).
// X-tile [32 m][512 k] = 32 KB LDS staged once; W direct from transposed Wt
// (coalesced 512B frags, L2; 0 conflicts); zero K-loop barriers.
// __launch_bounds__(256,3): VGPR cap ~168 -> acc[4]=64 + overhead fits WITHOUT
// spill (84 VGPR allocated, clean), 12 waves/CU, 3 blocks co-resident.
// R20 configuration — best measured (gemm_ln 46 us, total 71.85 us); R21-R24
// attempts (reg rotation, XCD swizzle, 16-wave variants, sched_barrier) all regressed.
__global__ __launch_bounds__(256, 3) void gemm_ln_kernel(const u16* __restrict__ Xagg, const u16* __restrict__ Wt,
                                                         const float* __restrict__ bias, const float* __restrict__ lnw,
                                                         const float* __restrict__ lnb, float* __restrict__ out) {
    __shared__ __align__(16) char smem[32768];   // X tile; stats overlay after K-loop
    float* Pss = (float*)smem;                   // [4 w][32 row][2]
    float* musig = (float*)(smem + 1024);        // [32 row][2]

    const int t = threadIdx.x;
    const int lane = t & 63, w = t >> 6, l31 = lane & 31, lh = lane >> 5;
    const size_t rb = (size_t)blockIdx.x * 32;
    const u16* Xab = Xagg + rb * DD;

    float bias_v[4], lnw_v[4], lnb_v[4];
    #pragma unroll
    for (int fh = 0; fh < 4; ++fh) {
        int h = w * 128 + fh * 32 + l31;
        bias_v[fh] = bias[h];
        lnw_v[fh] = lnw[h];
        lnb_v[fh] = lnb[h];
    }

    // stage X tile once: linear LDS dest, inverse-swizzled source (c' = c ^ (m&15))
    #pragma unroll
    for (int it = 0; it < 8; ++it) {
        int q = it * 256 + t;
        int m = q >> 6, cp = q & 63;
        gload16(Xab + (size_t)m * DD + ((cp ^ (m & 15)) * 8), (u16*)smem + q * 8);
    }
    __syncthreads();   // drains gloads; X read-only hereafter

    f32x16 acc[4];
    #pragma unroll
    for (int fh = 0; fh < 4; ++fh)
        #pragma unroll
        for (int r = 0; r < 16; ++r)
            acc[fh][r] = 0.f;

    const u16* al = (const u16*)smem;
    #pragma unroll
    for (int st = 0; st < 32; ++st) {
        const int gc = st * 2 + lh;               // 16B k-chunk 0..63
        bf16x8 af = *(const bf16x8*)(al + (l31 * 64 + (gc ^ (l31 & 15))) * 8);
        bf16x8 bw[4];
        #pragma unroll
        for (int fh = 0; fh < 4; ++fh) {
            int h = w * 128 + fh * 32 + l31;
            bw[fh] = *(const bf16x8*)(Wt + ((size_t)gc * HH + h) * 8);
        }
        #pragma unroll
        for (int fh = 0; fh < 4; ++fh)
            acc[fh] = __builtin_amdgcn_mfma_f32_32x32x16_bf16(af, bw[fh], acc[fh], 0, 0, 0);
    }
    __syncthreads();   // X dead; overlay stats

    // bias + per-row stats over this wave's 128 h
    float rs[16], rss[16];
    #pragma unroll
    for (int r = 0; r < 16; ++r) {
        float s = 0.f, ss = 0.f;
        #pragma unroll
        for (int fh = 0; fh < 4; ++fh) {
            float a = acc[fh][r] + bias_v[fh];
            acc[fh][r] = a;
            s += a; ss += a * a;
        }
        rs[r] = s; rss[r] = ss;
    }
    #pragma unroll
    for (int msk = 1; msk <= 16; msk <<= 1)
        #pragma unroll
        for (int r = 0; r < 16; ++r) {
            rs[r] += __shfl_xor(rs[r], msk);
            rss[r] += __shfl_xor(rss[r], msk);
        }
    if (l31 == 0) {
        #pragma unroll
        for (int r = 0; r < 16; ++r) {
            int rl = (r & 3) + 8 * (r >> 2) + 4 * lh;
            float2 v; v.x = rs[r]; v.y = rss[r];
            *(float2*)(Pss + (w * 32 + rl) * 2) = v;
        }
    }
    __syncthreads();
    if (t < 32) {
        float s = 0.f, ss = 0.f;
        #pragma unroll
        for (int q = 0; q < 4; ++q) {
            float2 v = *(const float2*)(Pss + (q * 32 + t) * 2);
            s += v.x; ss += v.y;
        }
        float mean = s * (1.0f / 512.0f);
        float var = ss * (1.0f / 512.0f) - mean * mean;
        float2 mz; mz.x = mean; mz.y = rsqrtf(var + 1e-5f);
        *(float2*)(musig + t * 2) = mz;
    }
    __syncthreads();

    #pragma unroll
    for (int r = 0; r < 16; ++r) {
        int rl = (r & 3) + 8 * (r >> 2) + 4 * lh;
        float2 mz = *(const float2*)(musig + rl * 2);
        #pragma unroll
        for (int fh = 0; fh < 4; ++fh) {
            float xn = (acc[fh][r] - mz.x) * mz.y * lnw_v[fh] + lnb_v[fh];
            out[(rb + rl) * HH + w * 128 + fh * 32 + l31] = 1.0f / (1.0f + __expf(-xn));
        }
    }
}

extern "C" void kernel_launch(void* const* d_in, const int* in_sizes, int n_in,
                              void* d_out, int out_size, void* d_ws, size_t ws_size,
                              hipStream_t stream) {
    const float* X = (const float*)d_in[0];
    const float* A = (const float*)d_in[1];
    const float* W = (const float*)d_in[2];
    const float* bias = (const float*)d_in[3];
    const float* lnw = (const float*)d_in[4];
    const float* lnb = (const float*)d_in[5];
    float* out = (float*)d_out;

    u16* Xagg = (u16*)d_ws;                                  // B*N*D bf16 = 32 MB
    u16* Wt = (u16*)d_ws + (size_t)BB * NN * DD;             // transposed W bf16 = 512 KB

    hipLaunchKernelGGL(wconv_kernel, dim3(256), dim3(256), 0, stream, W, Wt);
    hipLaunchKernelGGL(agg_kernel, dim3(256), dim3(512), 0, stream, X, A, Xagg);
    hipLaunchKernelGGL(gemm_ln_kernel, dim3(1024), dim3(256), 0, stream, Xagg, Wt, bias, lnw, lnb, out);
}